// Round 10
// baseline (441.288 us; speedup 1.0000x reference)
//
#include <hip/hip_runtime.h>

// Problem constants (match reference.py)
#define NCLASS 100
#define DDIM   512
#define NROWS  131072

#define RPB      1024               // rows per block (row-chunk)
#define NRC      (NROWS / RPB)      // 128 row-chunks
#define NHALF    2                  // column halves (256 cols each)
#define ATHREADS 1024               // 16 waves
#define AWAVES   16
#define RPW      (RPB / AWAVES)     // 64 contiguous rows per wave

// Native LDS float atomic (ds_add_f32, fire-and-forget). Plain atomicAdd on
// __shared__ float compiles to a CAS retry loop (R1: 966 us); unsafeAtomicAdd
// emits the hardware instruction (global twin verified native in R3).
__device__ __forceinline__ void ldsAddF(float* p, float v) {
    unsafeAtomicAdd(p, v);
}

// ---------------------------------------------------------------------------
// Kernel 1: sequential-stream accumulation. Block = (1024-row chunk) x
// (256-col half); wave w streams rows [w*64, w*64+64) with float4/lane,
// depth-4 ring. Per row: 4x ds_add_f32 into swizzled per-class LDS
// accumulators (conflict-free: pos = (col&3)*64 + lane) + 1x ds_add_f32 of
// the lane's sum-of-squares. No sort, no gather, no global atomics.
// The col->pos swizzle is never undone: finalize only needs sum_col (.)^2.
// ---------------------------------------------------------------------------
__global__ __launch_bounds__(ATHREADS) void icv_accum_kernel(
    const float* __restrict__ feat,     // [NROWS][DDIM]
    const int*   __restrict__ labels,   // [NROWS]
    float*       __restrict__ sums_p,   // [NRC][NCLASS][DDIM] (swizzled cols)
    float*       __restrict__ sq_p,     // [NRC][NHALF][NCLASS]
    int*         __restrict__ cnt_p,    // [NRC][NCLASS]
    int*         __restrict__ sync_cnt)
{
    __shared__ float s_acc[NCLASS * 256];   // 100 KB
    __shared__ float s_sqp[NCLASS * 64];    // 25.6 KB
    __shared__ int   s_lab[RPB];            // 4 KB
    __shared__ int   s_cnt[NCLASS];

    const int tid  = threadIdx.x;
    const int wave = tid >> 6;
    const int lane = tid & 63;
    const int half = blockIdx.x & 1;
    const int rc   = blockIdx.x >> 1;
    const int row0 = rc * RPB;

    for (int i = tid; i < NCLASS * 256; i += ATHREADS) s_acc[i] = 0.f;
    for (int i = tid; i < NCLASS * 64;  i += ATHREADS) s_sqp[i] = 0.f;
    if (tid < NCLASS) s_cnt[tid] = 0;
    if (blockIdx.x == 0 && tid == 0) *sync_cnt = 0;    // re-init every call
    s_lab[tid] = labels[row0 + tid];                   // coalesced
    __syncthreads();
    if (half == 0) atomicAdd(&s_cnt[s_lab[tid]], 1);   // int: native ds_add

    // ---- sequential stream: 64 contiguous rows per wave ----
    const float4* fp = (const float4*)feat
                     + (size_t)(row0 + wave * RPW) * (DDIM / 4)
                     + half * 64 + lane;               // row step = 128 f4
    const int lbase = wave * RPW;

#define PROC(X, LAB) do {                                                     \
        float* base_ = &s_acc[(LAB) * 256 + lane];                            \
        ldsAddF(base_ + 0,   (X).x);                                          \
        ldsAddF(base_ + 64,  (X).y);                                          \
        ldsAddF(base_ + 128, (X).z);                                          \
        ldsAddF(base_ + 192, (X).w);                                          \
        const float sqv_ = fmaf((X).x, (X).x, fmaf((X).y, (X).y,              \
                           fmaf((X).z, (X).z, (X).w * (X).w)));               \
        ldsAddF(&s_sqp[(LAB) * 64 + lane], sqv_);                             \
    } while (0)

    float4 r0 = fp[0 * 128], r1 = fp[1 * 128], r2 = fp[2 * 128], r3 = fp[3 * 128];
    int    l0 = s_lab[lbase + 0], l1 = s_lab[lbase + 1];
    int    l2 = s_lab[lbase + 2], l3 = s_lab[lbase + 3];

    for (int k = 0; k < RPW; k += 4) {
        PROC(r0, l0);
        if (k + 4 < RPW) { r0 = fp[(size_t)(k + 4) * 128]; l0 = s_lab[lbase + k + 4]; }
        PROC(r1, l1);
        if (k + 5 < RPW) { r1 = fp[(size_t)(k + 5) * 128]; l1 = s_lab[lbase + k + 5]; }
        PROC(r2, l2);
        if (k + 6 < RPW) { r2 = fp[(size_t)(k + 6) * 128]; l2 = s_lab[lbase + k + 6]; }
        PROC(r3, l3);
        if (k + 7 < RPW) { r3 = fp[(size_t)(k + 7) * 128]; l3 = s_lab[lbase + k + 7]; }
    }
#undef PROC
    __syncthreads();

    // ---- flush: plain coalesced stores to per-chunk partials ----
    for (int i = tid; i < NCLASS * 64; i += ATHREADS) {
        const int c = i >> 6;
        const int q = i & 63;
        ((float4*)(sums_p + (size_t)(rc * NCLASS + c) * DDIM + half * 256))[q] =
            ((const float4*)(s_acc + c * 256))[q];
    }
    for (int c = wave; c < NCLASS; c += AWAVES) {
        float v = s_sqp[c * 64 + lane];
        v += __shfl_xor(v, 32, 64); v += __shfl_xor(v, 16, 64);
        v += __shfl_xor(v,  8, 64); v += __shfl_xor(v,  4, 64);
        v += __shfl_xor(v,  2, 64); v += __shfl_xor(v,  1, 64);
        if (lane == 0) sq_p[(rc * NHALF + half) * NCLASS + c] = v;
    }
    if (half == 0 && tid < NCLASS) cnt_p[rc * NCLASS + tid] = s_cnt[tid];
}

// ---------------------------------------------------------------------------
// Kernel 2: per-class reduction of partials -> trace/valid, fused with the
// final valid-mean via last-block pattern (device-scope fence + atomic).
// ---------------------------------------------------------------------------
__global__ __launch_bounds__(512) void icv_reduce_kernel(
    const float* __restrict__ sums_p,   // [NRC][NCLASS][DDIM]
    const float* __restrict__ sq_p,     // [NRC][NHALF][NCLASS]
    const int*   __restrict__ cnt_p,    // [NRC][NCLASS]
    float*       __restrict__ cls_out,  // [NCLASS][2]
    int*         __restrict__ sync_cnt,
    float*       __restrict__ out)
{
    __shared__ float red[3][8];
    __shared__ float fin[2][8];
    __shared__ int   s_last;

    const int c    = blockIdx.x;
    const int t    = threadIdx.x;
    const int wave = t >> 6;
    const int lane = t & 63;

    // thread t owns (swizzled) column t of class c, summed over row-chunks
    float s = 0.f;
    const float* p = sums_p + (size_t)c * DDIM + t;
    #pragma unroll 8
    for (int ch = 0; ch < NRC; ++ch)
        s += p[(size_t)ch * (NCLASS * DDIM)];

    float v1 = s * s;                                          // -> ||sum_c||^2
    float v2 = (t < NRC * NHALF) ? sq_p[t * NCLASS + c] : 0.f;
    float v3 = (t < NRC) ? (float)cnt_p[t * NCLASS + c] : 0.f;
    #pragma unroll
    for (int off = 32; off > 0; off >>= 1) {
        v1 += __shfl_xor(v1, off, 64);
        v2 += __shfl_xor(v2, off, 64);
        v3 += __shfl_xor(v3, off, 64);
    }
    if (lane == 0) { red[0][wave] = v1; red[1][wave] = v2; red[2][wave] = v3; }
    __syncthreads();

    if (t == 0) {
        float n2 = 0.f, sq = 0.f, n = 0.f;
        #pragma unroll
        for (int w = 0; w < 8; ++w) { n2 += red[0][w]; sq += red[1][w]; n += red[2][w]; }
        const float safe  = fmaxf(n, 1.f);
        const float ssd   = sq - n2 / safe;        // sq - n*||sums/n||^2
        const float trace = ssd / fmaxf(n - 1.f, 1.f);
        const bool  valid = (n >= 2.f);
        cls_out[c * 2 + 0] = valid ? trace : 0.f;
        cls_out[c * 2 + 1] = valid ? 1.f : 0.f;
        __threadfence();                           // release class result
        const int done = atomicAdd(sync_cnt, 1);   // device-scope
        s_last = (done == NCLASS - 1) ? 1 : 0;
    }
    __syncthreads();

    if (s_last) {                                  // uniform across block
        __threadfence();                           // acquire others' results
        float tv = 0.f, vv = 0.f;
        if (t < NCLASS) {
            const volatile float* cv = (const volatile float*)cls_out;
            tv = cv[t * 2 + 0];
            vv = cv[t * 2 + 1];
        }
        #pragma unroll
        for (int off = 32; off > 0; off >>= 1) {
            tv += __shfl_xor(tv, off, 64);
            vv += __shfl_xor(vv, off, 64);
        }
        if (lane == 0) { fin[0][wave] = tv; fin[1][wave] = vv; }
        __syncthreads();
        if (t == 0) {
            float tot = 0.f, vc = 0.f;
            #pragma unroll
            for (int w = 0; w < 8; ++w) { tot += fin[0][w]; vc += fin[1][w]; }
            out[0] = (vc > 0.f) ? (tot / fmaxf(vc, 1.f)) : 0.f;
        }
    }
}

extern "C" void kernel_launch(void* const* d_in, const int* in_sizes, int n_in,
                              void* d_out, int out_size, void* d_ws, size_t ws_size,
                              hipStream_t stream) {
    const float* feat   = (const float*)d_in[0];
    const int*   labels = (const int*)d_in[1];
    float* out = (float*)d_out;

    // Workspace (all slots written unconditionally every call -> no memset):
    float* sums_p  = (float*)d_ws;                              // 26.2 MB
    float* sq_p    = sums_p + (size_t)NRC * NCLASS * DDIM;      // 102 KB
    int*   cnt_p   = (int*)(sq_p + NRC * NHALF * NCLASS);       // 51 KB
    float* cls_out = (float*)(cnt_p + NRC * NCLASS);
    int*   sync_cnt= (int*)(cls_out + NCLASS * 2);

    icv_accum_kernel<<<dim3(NRC * NHALF), ATHREADS, 0, stream>>>(
        feat, labels, sums_p, sq_p, cnt_p, sync_cnt);
    icv_reduce_kernel<<<dim3(NCLASS), 512, 0, stream>>>(
        sums_p, sq_p, cnt_p, cls_out, sync_cnt, out);
}

// Round 11
// 80.711 us; speedup vs baseline: 5.4675x; 5.4675x over previous
//
#include <hip/hip_runtime.h>

// Problem constants (match reference.py)
#define NCLASS 100
#define DDIM   512
#define NROWS  131072

#define CHUNK    2048               // rows per chunk
#define NCHUNK   (NROWS / CHUNK)    // 64
#define NSPLIT   8                  // row-splits per chunk (full row per wave)
#define AWAVES   8                  // waves per accum block
#define WSLOTS   (NSPLIT * AWAVES)  // 64 wave-slots per chunk
#define SPAN     (CHUNK / WSLOTS)   // 32 rows nominal per wave-slot
#define ATHREADS 512
#define STHREADS 1024

__device__ __forceinline__ void gAtomicAddF(float* p, float v) {
    unsafeAtomicAdd(p, v);          // native global_atomic_add_f32
}

// ---------------------------------------------------------------------------
// Kernel 0: per-chunk counting sort of labels (labels-only). Emits class-
// sorted global row ids, class offsets, counts, and 64 per-chunk wave-slot
// class spans. MIDPOINT snapping: class c belongs to the slot containing
// (off[c]+off[c+1])/2 -> quantization error centered, ~halved wave imbalance
// vs start-snapping. Also zero-inits cls accumulators + sync counter.
// ---------------------------------------------------------------------------
__global__ __launch_bounds__(STHREADS) void icv_sort_kernel(
    const int* __restrict__ labels,
    int*   __restrict__ rows_g,     // [NCHUNK][CHUNK]
    int*   __restrict__ off_g,      // [NCHUNK][NCLASS+1]
    int*   __restrict__ cnt_p,      // [NCHUNK][NCLASS]
    int*   __restrict__ span_g,     // [NCHUNK][WSLOTS][2]
    float* __restrict__ cls_norm2,  // [NCLASS] (atomic-accumulated by reduce)
    int*   __restrict__ sync_cnt)
{
    __shared__ int s_cnt[NCLASS];
    __shared__ int s_off[NCLASS + 1];
    __shared__ int s_pos[NCLASS];
    __shared__ int s_scan[128];
    __shared__ int s_rows[CHUNK];

    const int tid   = threadIdx.x;
    const int chunk = blockIdx.x;
    const int row0  = chunk * CHUNK;

    if (tid < NCLASS) s_cnt[tid] = 0;
    if (chunk == 0) {                              // re-init every call
        if (tid < NCLASS) cls_norm2[tid] = 0.f;
        if (tid == 0) *sync_cnt = 0;
    }
    __syncthreads();

    const int lab0 = labels[row0 + tid];           // coalesced, 2 rows/thread
    const int lab1 = labels[row0 + STHREADS + tid];
    atomicAdd(&s_cnt[lab0], 1);
    atomicAdd(&s_cnt[lab1], 1);
    __syncthreads();

    // exclusive prefix over 100 bins (128-wide Hillis-Steele)
    if (tid < 128) s_scan[tid] = (tid < NCLASS) ? s_cnt[tid] : 0;
    __syncthreads();
    #pragma unroll
    for (int d = 1; d < 128; d <<= 1) {
        int v = 0;
        if (tid < 128) { v = s_scan[tid]; if (tid >= d) v += s_scan[tid - d]; }
        __syncthreads();
        if (tid < 128) s_scan[tid] = v;
        __syncthreads();
    }
    if (tid < NCLASS) { const int e = s_scan[tid] - s_cnt[tid]; s_off[tid] = e; s_pos[tid] = e; }
    if (tid == NCLASS) s_off[NCLASS] = CHUNK;
    __syncthreads();

    { const int p0 = atomicAdd(&s_pos[lab0], 1); s_rows[p0] = row0 + tid; }
    { const int p1 = atomicAdd(&s_pos[lab1], 1); s_rows[p1] = row0 + STHREADS + tid; }

    // wave-slot class spans via MIDPOINT owner: ow(c) = min(mid_c/SPAN, WSLOTS-1);
    // mid_c monotone in c -> contiguous class ranges, full partition.
    if (tid < WSLOTS) {
        int cf = NCLASS, ce = NCLASS;
        for (int c = 0; c < NCLASS; ++c) {
            const int mid = (s_off[c] + s_off[c + 1]) >> 1;
            int ow = mid / SPAN; if (ow > WSLOTS - 1) ow = WSLOTS - 1;
            if (ow == tid && cf == NCLASS) cf = c;
            if (ow > tid) { ce = c; break; }
        }
        if (cf > ce) cf = ce;                      // empty slot
        span_g[(chunk * WSLOTS + tid) * 2 + 0] = cf;
        span_g[(chunk * WSLOTS + tid) * 2 + 1] = ce;
    }
    __syncthreads();

    rows_g[chunk * CHUNK + tid]            = s_rows[tid];
    rows_g[chunk * CHUNK + STHREADS + tid] = s_rows[STHREADS + tid];
    if (tid < NCLASS) {
        off_g[chunk * (NCLASS + 1) + tid] = s_off[tid];
        cnt_p[chunk * NCLASS + tid]       = s_cnt[tid];
    }
    if (tid == NCLASS) off_g[chunk * (NCLASS + 1) + NCLASS] = CHUNK;
}

// ---------------------------------------------------------------------------
// Kernel 1: pure streaming accumulation, FULL-ROW granule (identical to R8's
// best: 64 chunks x 8 splits = 512 blocks of 512 threads, 2 blocks/CU,
// 2x float4 per lane per row, depth-4 ring, register accumulation,
// per-class flush = plain coalesced stores).
// ---------------------------------------------------------------------------
__global__ __launch_bounds__(ATHREADS, 4) void icv_accum_kernel(
    const float* __restrict__ feat,     // [NROWS][DDIM]
    const int*   __restrict__ rows_g,
    const int*   __restrict__ off_g,
    const int*   __restrict__ span_g,
    float*       __restrict__ sums_p,   // [NCHUNK][NCLASS][DDIM]
    float*       __restrict__ sq_p)     // [NCHUNK][NCLASS]
{
    __shared__ int s_rows[CHUNK];       // 8 KB
    __shared__ int s_off[NCLASS + 1];

    const int tid   = threadIdx.x;
    const int wave  = tid >> 6;
    const int lane  = tid & 63;
    const int b     = blockIdx.x;
    const int chunk = b >> 3;
    const int split = b & 7;

    #pragma unroll
    for (int k = 0; k < CHUNK / ATHREADS; ++k)
        s_rows[k * ATHREADS + tid] = rows_g[chunk * CHUNK + k * ATHREADS + tid];
    if (tid < NCLASS + 1) s_off[tid] = off_g[chunk * (NCLASS + 1) + tid];
    __syncthreads();

    const int ws = split * AWAVES + wave;
    const int cf = span_g[(chunk * WSLOTS + ws) * 2 + 0];
    const int ce = span_g[(chunk * WSLOTS + ws) * 2 + 1];
    const int i0 = s_off[cf];
    const int i1 = s_off[ce];

    const float4* f4 = (const float4*)feat;        // row stride DDIM/4 = 128

    int    c    = cf;
    int    cend = (c < ce) ? s_off[c + 1] : (CHUNK + 1);
    float4 accA = make_float4(0.f, 0.f, 0.f, 0.f);
    float4 accB = make_float4(0.f, 0.f, 0.f, 0.f);
    float  sq   = 0.f;

#define LOADA(idx) f4[(size_t)s_rows[(idx)] * (DDIM / 4) + lane]
#define LOADB(idx) f4[(size_t)s_rows[(idx)] * (DDIM / 4) + 64 + lane]

#define FLUSH() do {                                                          \
        float s_ = sq;                                                        \
        s_ += __shfl_xor(s_, 32, 64); s_ += __shfl_xor(s_, 16, 64);           \
        s_ += __shfl_xor(s_,  8, 64); s_ += __shfl_xor(s_,  4, 64);           \
        s_ += __shfl_xor(s_,  2, 64); s_ += __shfl_xor(s_,  1, 64);           \
        float4* dst_ = (float4*)(sums_p                                       \
            + ((size_t)(chunk * NCLASS + c) * DDIM));                         \
        dst_[lane]      = accA;                                               \
        dst_[64 + lane] = accB;                                               \
        if (lane == 0) sq_p[chunk * NCLASS + c] = s_;                         \
        accA = make_float4(0.f, 0.f, 0.f, 0.f);                               \
        accB = make_float4(0.f, 0.f, 0.f, 0.f);                               \
        sq = 0.f;                                                             \
        ++c;                                                                  \
        cend = (c < ce) ? s_off[c + 1] : (CHUNK + 1);                         \
    } while (0)

#define STEP(K, RA, RB) {                                                     \
        const int i_ = ib + (K);                                              \
        if (i_ < i1) {                                                        \
            while (i_ >= cend) FLUSH();                                       \
            const float4 a_ = RA;                                             \
            const float4 b_ = RB;                                             \
            const int ip_ = i_ + 4;                                           \
            if (ip_ < i1) { RA = LOADA(ip_); RB = LOADB(ip_); }               \
            accA.x += a_.x; accA.y += a_.y; accA.z += a_.z; accA.w += a_.w;   \
            accB.x += b_.x; accB.y += b_.y; accB.z += b_.z; accB.w += b_.w;   \
            sq = fmaf(a_.x, a_.x, fmaf(a_.y, a_.y,                            \
                 fmaf(a_.z, a_.z, fmaf(a_.w, a_.w, sq))));                    \
            sq = fmaf(b_.x, b_.x, fmaf(b_.y, b_.y,                            \
                 fmaf(b_.z, b_.z, fmaf(b_.w, b_.w, sq))));                    \
        }                                                                     \
    }

    float4 r0a = make_float4(0.f, 0.f, 0.f, 0.f), r0b = r0a;
    float4 r1a = r0a, r1b = r0a, r2a = r0a, r2b = r0a, r3a = r0a, r3b = r0a;
    if (i0 + 0 < i1) { r0a = LOADA(i0 + 0); r0b = LOADB(i0 + 0); }
    if (i0 + 1 < i1) { r1a = LOADA(i0 + 1); r1b = LOADB(i0 + 1); }
    if (i0 + 2 < i1) { r2a = LOADA(i0 + 2); r2b = LOADB(i0 + 2); }
    if (i0 + 3 < i1) { r3a = LOADA(i0 + 3); r3b = LOADB(i0 + 3); }

    for (int ib = i0; ib < i1; ib += 4) {
        STEP(0, r0a, r0b)
        STEP(1, r1a, r1b)
        STEP(2, r2a, r2b)
        STEP(3, r3a, r3b)
    }
    while (c < ce) FLUSH();                        // tail incl. empty classes
#undef STEP
#undef FLUSH
#undef LOADA
#undef LOADB
}

// ---------------------------------------------------------------------------
// Kernel 2: parallelized fused reduce. Grid = NCLASS x 4 column-quarters
// (400 blocks x 128 threads). Each block sums its 128 columns over 64 chunks,
// squares, block-reduces, and atomically adds into cls_norm2[c]. q==0 blocks
// also reduce sq/cnt. Last of 400 blocks computes the final valid-mean.
// ---------------------------------------------------------------------------
__global__ __launch_bounds__(128) void icv_reduce_kernel(
    const float* __restrict__ sums_p,   // [NCHUNK][NCLASS][DDIM]
    const float* __restrict__ sq_p,     // [NCHUNK][NCLASS]
    const int*   __restrict__ cnt_p,    // [NCHUNK][NCLASS]
    float*       __restrict__ cls_norm2,// [NCLASS]
    float*       __restrict__ cls_sq,   // [NCLASS]
    float*       __restrict__ cls_n,    // [NCLASS]
    int*         __restrict__ sync_cnt,
    float*       __restrict__ out)
{
    __shared__ float sred[2];
    __shared__ float fin[2][2];
    __shared__ int   s_last;

    const int c = blockIdx.x >> 2;
    const int q = blockIdx.x & 3;
    const int t = threadIdx.x;          // 0..127

    // thread t owns column q*128+t of class c, summed over chunks
    float s = 0.f;
    const float* p = sums_p + (size_t)c * DDIM + (q * 128 + t);
    #pragma unroll 16
    for (int ch = 0; ch < NCHUNK; ++ch)
        s += p[(size_t)ch * (NCLASS * DDIM)];

    float v = s * s;
    v += __shfl_xor(v, 32, 64); v += __shfl_xor(v, 16, 64);
    v += __shfl_xor(v,  8, 64); v += __shfl_xor(v,  4, 64);
    v += __shfl_xor(v,  2, 64); v += __shfl_xor(v,  1, 64);
    if ((t & 63) == 0) sred[t >> 6] = v;

    if (t < 64 && q == 0) {             // wave 0: sq & count reductions
        float v2 = (t < NCHUNK) ? sq_p[t * NCLASS + c] : 0.f;
        float v3 = (t < NCHUNK) ? (float)cnt_p[t * NCLASS + c] : 0.f;
        v2 += __shfl_xor(v2, 32, 64); v3 += __shfl_xor(v3, 32, 64);
        v2 += __shfl_xor(v2, 16, 64); v3 += __shfl_xor(v3, 16, 64);
        v2 += __shfl_xor(v2,  8, 64); v3 += __shfl_xor(v3,  8, 64);
        v2 += __shfl_xor(v2,  4, 64); v3 += __shfl_xor(v3,  4, 64);
        v2 += __shfl_xor(v2,  2, 64); v3 += __shfl_xor(v3,  2, 64);
        v2 += __shfl_xor(v2,  1, 64); v3 += __shfl_xor(v3,  1, 64);
        if (t == 0) { cls_sq[c] = v2; cls_n[c] = v3; }
    }
    __syncthreads();

    if (t == 0) {
        gAtomicAddF(&cls_norm2[c], sred[0] + sred[1]);
        __threadfence();                           // release
        const int done = atomicAdd(sync_cnt, 1);   // device-scope
        s_last = (done == NCLASS * 4 - 1) ? 1 : 0;
    }
    __syncthreads();

    if (s_last) {                                  // uniform across block
        __threadfence();                           // acquire
        float tv = 0.f, vv = 0.f;
        if (t < NCLASS) {
            const volatile float* vn = cls_norm2;
            const volatile float* vq = cls_sq;
            const volatile float* vc = cls_n;
            const float n    = vc[t];
            const float n2   = vn[t];
            const float sqv  = vq[t];
            const float safe = fmaxf(n, 1.f);
            const float ssd  = sqv - n2 / safe;    // sq - n*||sums/n||^2
            const float tr   = ssd / fmaxf(n - 1.f, 1.f);
            const bool  valid = (n >= 2.f);
            tv = valid ? tr : 0.f;
            vv = valid ? 1.f : 0.f;
        }
        tv += __shfl_xor(tv, 32, 64); vv += __shfl_xor(vv, 32, 64);
        tv += __shfl_xor(tv, 16, 64); vv += __shfl_xor(vv, 16, 64);
        tv += __shfl_xor(tv,  8, 64); vv += __shfl_xor(vv,  8, 64);
        tv += __shfl_xor(tv,  4, 64); vv += __shfl_xor(vv,  4, 64);
        tv += __shfl_xor(tv,  2, 64); vv += __shfl_xor(vv,  2, 64);
        tv += __shfl_xor(tv,  1, 64); vv += __shfl_xor(vv,  1, 64);
        if ((t & 63) == 0) { fin[0][t >> 6] = tv; fin[1][t >> 6] = vv; }
        __syncthreads();
        if (t == 0) {
            const float tot = fin[0][0] + fin[0][1];
            const float vcn = fin[1][0] + fin[1][1];
            out[0] = (vcn > 0.f) ? (tot / fmaxf(vcn, 1.f)) : 0.f;
        }
    }
}

extern "C" void kernel_launch(void* const* d_in, const int* in_sizes, int n_in,
                              void* d_out, int out_size, void* d_ws, size_t ws_size,
                              hipStream_t stream) {
    const float* feat   = (const float*)d_in[0];
    const int*   labels = (const int*)d_in[1];
    float* out = (float*)d_out;

    // Workspace (all result slots written unconditionally -> no memset needed;
    // cls_norm2/sync_cnt zero-inited by the sort kernel each call):
    float* sums_p    = (float*)d_ws;                              // 13.1 MB
    float* sq_p      = sums_p + (size_t)NCHUNK * NCLASS * DDIM;   // 26 KB
    int*   cnt_p     = (int*)(sq_p + NCHUNK * NCLASS);            // 26 KB
    int*   rows_g    = cnt_p + NCHUNK * NCLASS;                   // 524 KB
    int*   off_g     = rows_g + NCHUNK * CHUNK;                   // 26 KB
    int*   span_g    = off_g + NCHUNK * (NCLASS + 1);             // 32 KB
    float* cls_norm2 = (float*)(span_g + NCHUNK * WSLOTS * 2);
    float* cls_sq    = cls_norm2 + NCLASS;
    float* cls_n     = cls_sq + NCLASS;
    int*   sync_cnt  = (int*)(cls_n + NCLASS);

    icv_sort_kernel<<<dim3(NCHUNK), STHREADS, 0, stream>>>(
        labels, rows_g, off_g, cnt_p, span_g, cls_norm2, sync_cnt);
    icv_accum_kernel<<<dim3(NCHUNK * NSPLIT), ATHREADS, 0, stream>>>(
        feat, rows_g, off_g, span_g, sums_p, sq_p);
    icv_reduce_kernel<<<dim3(NCLASS * 4), 128, 0, stream>>>(
        sums_p, sq_p, cnt_p, cls_norm2, cls_sq, cls_n, sync_cnt, out);
}